// Round 5
// baseline (630.277 us; speedup 1.0000x reference)
//
#include <hip/hip_runtime.h>

#define D 64
#define NPB 128              // nodes per bucket (dstLocal: 7 bits)
#define NPB_SHIFT 7
#define MAXB 1024            // bound on bucket count B = ceil(N/NPB)
#define SCATTER_T 512
#define CHUNK_MAX 4704       // max edges staged per scatter block (LDS-sized)
#define SCQ 10               // per-thread reg-staged edges (SCQ*512 >= CHUNK_MAX)
#define CAPB 2560            // fixed per-bucket capacity in adjB (mean 1534)
#define GT 512               // accum_gather block size (8 waves)

// round-to-nearest-even fp32 -> bf16 (values are finite/normal here)
__device__ inline unsigned f2bf(float f) {
    unsigned u = __float_as_uint(f);
    return (u + 0x7FFFu + ((u >> 16) & 1u)) >> 16;
}

// ---------------------------------------------------------------------------
// zero helpers (ws is poisoned 0xAA every launch)
// ---------------------------------------------------------------------------
__global__ void zero_i_kernel(int* __restrict__ p, int n) {
    int i = blockIdx.x * blockDim.x + threadIdx.x;
    if (i < n) p[i] = 0;
}
__global__ void zero_f4_kernel(float4* __restrict__ p, int n4) {
    int i = blockIdx.x * blockDim.x + threadIdx.x;
    if (i < n4) p[i] = make_float4(0.f, 0.f, 0.f, 0.f);
}

// ---------------------------------------------------------------------------
// bucket scatter (standalone; r3 fusion was neutral-to-negative).
// Reg-stage edges (single global pass) -> LDS chunk histogram -> local excl
// scan -> reserve per-bucket ranges from cursors -> LDS counting sort ->
// coalesced write-out in ~48B runs. Overflow past CAPB -> ovf list (cold).
// Packing: x = src | dstLocal<<20, y = w bits.
// ---------------------------------------------------------------------------
__global__ __launch_bounds__(SCATTER_T) void bucket_scatter_kernel(
        const int* __restrict__ src, const int* __restrict__ dst,
        const float* __restrict__ w, int* __restrict__ cursor,
        int* __restrict__ ovfCnt, int4* __restrict__ ovf,
        int2* __restrict__ adjB, int E, int B) {
    __shared__ int lc[MAXB];
    __shared__ int lpre[MAXB];
    __shared__ int lbase[MAXB];
    __shared__ int lfill[MAXB];
    __shared__ int sums[SCATTER_T];
    __shared__ unsigned short sb[CHUNK_MAX];
    __shared__ int2 stage[CHUNK_MAX];

    int t = threadIdx.x;
    int chunk = (E + gridDim.x - 1) / gridDim.x;   // <= CHUNK_MAX by host calc
    int lo = blockIdx.x * chunk, hi = min(lo + chunk, E);
    int n = hi - lo;
    if (n <= 0) return;

    for (int i = t; i < MAXB; i += SCATTER_T) { lc[i] = 0; lfill[i] = 0; }

    // reg-stage this thread's edges (one global pass over dst/src/w)
    int rd[SCQ]; int rs[SCQ]; float rw[SCQ];
#pragma unroll
    for (int q = 0; q < SCQ; ++q) {
        int e = lo + t + q * SCATTER_T;
        bool v = e < hi;
        rd[q] = v ? dst[e] : -1;
        rs[q] = v ? src[e] : 0;
        rw[q] = v ? w[e] : 0.f;
    }
    __syncthreads();

    // A1: chunk histogram
#pragma unroll
    for (int q = 0; q < SCQ; ++q)
        if (rd[q] >= 0) atomicAdd(&lc[rd[q] >> NPB_SHIFT], 1);
    __syncthreads();

    // A2: exclusive scan of lc[0..MAXB) (2/thread + H-S on 512)
    int s0 = lc[2 * t], s1 = lc[2 * t + 1];
    sums[t] = s0 + s1;
    __syncthreads();
    for (int st = 1; st < SCATTER_T; st <<= 1) {
        int v = (t >= st) ? sums[t - st] : 0;
        __syncthreads();
        sums[t] += v;
        __syncthreads();
    }
    int ex = (t == 0) ? 0 : sums[t - 1];
    lpre[2 * t] = ex;
    lpre[2 * t + 1] = ex + s0;
    __syncthreads();

    // A3: reserve per-bucket ranges (1 global atomic per nonempty bucket)
    for (int i = t; i < B; i += SCATTER_T) {
        int c = lc[i];
        lbase[i] = c ? atomicAdd(&cursor[i], c) : 0;
    }
    __syncthreads();

    // B: place into locally-sorted LDS slots
#pragma unroll
    for (int q = 0; q < SCQ; ++q) {
        int d = rd[q];
        if (d >= 0) {
            int bkt = d >> NPB_SHIFT;
            int i = lpre[bkt] + atomicAdd(&lfill[bkt], 1);
            stage[i] = make_int2(rs[q] | ((d & (NPB - 1)) << 20),
                                 __float_as_int(rw[q]));
            sb[i] = (unsigned short)bkt;
        }
    }
    __syncthreads();

    // C: coalesced write-out in locally-sorted order
    for (int i = t; i < n; i += SCATTER_T) {
        int bkt = sb[i];
        int2 v = stage[i];
        int pos = lbase[bkt] + (i - lpre[bkt]);
        if (pos < CAPB) {
            adjB[(size_t)bkt * CAPB + pos] = v;
        } else {                               // cold: bucket overflow
            int oi = atomicAdd(ovfCnt, 1);
            ovf[oi] = make_int4(v.x, v.y, bkt, 0);
        }
    }
}

// ---------------------------------------------------------------------------
// accum gather: one block per bucket, NO sorting. Stream the bucket's adjB
// slice (staged 512 edges at a time into LDS); each HALF-WAVE takes an edge,
// reads its 128B proj row, and LDS-atomicAdds into acc[node][dim]. Mapping:
// lane k owns dims {k, k+32} and proj word j packs (col j, col j+32), so
// the two ds_add_f32 per lane hit bank k -> exactly 2 lanes/bank per wave64
// (free), independent of which nodes the halves process. Final: barrier +
// coalesced float4 writeout of all 128 rows. LDS 36.3KB -> 4 blocks/CU.
// Overflow entries (cursor > CAPB, never for this input) are accumulated
// into acc before writeout (no global atomics needed).
// ---------------------------------------------------------------------------
__global__ __launch_bounds__(GT) void accum_gather_kernel(
        const int2* __restrict__ adjB, const int* __restrict__ cursor,
        const int* __restrict__ ovfCnt, const int4* __restrict__ ovf,
        const unsigned* __restrict__ projW, float* __restrict__ out, int N) {
    __shared__ float acc[NPB * D];       // 32 KB
    __shared__ int2 ebuf[GT];            // 4 KB
    __shared__ int sOvf;

    int b = blockIdx.x;
    int t = threadIdx.x;
    int m = min(cursor[b], CAPB);
    const int2* base = adjB + (size_t)b * CAPB;

#pragma unroll
    for (int i = 0; i < (NPB * D / 4) / GT; ++i)
        ((float4*)acc)[t + i * GT] = make_float4(0.f, 0.f, 0.f, 0.f);
    if (t == 0) sOvf = *ovfCnt;
    __syncthreads();

    int hw = t >> 5;        // half-wave 0..15
    int k = t & 31;         // lane owns dims {k, k+32}

    for (int base_e = 0; base_e < m; base_e += GT) {
        int nb = min(GT, m - base_e);
        if (base_e + t < m) ebuf[t] = base[base_e + t];
        __syncthreads();
        int j = hw;
        for (; j + 16 < nb; j += 32) {   // 2 edges in flight per half-wave
            int2 a0 = ebuf[j];
            int2 a1 = ebuf[j + 16];
            unsigned p0 = projW[(size_t)(a0.x & 0xFFFFF) * 32 + k];
            unsigned p1 = projW[(size_t)(a1.x & 0xFFFFF) * 32 + k];
            float w0 = __int_as_float(a0.y);
            float w1 = __int_as_float(a1.y);
            int d0 = ((unsigned)a0.x) >> 20;
            int d1 = ((unsigned)a1.x) >> 20;
            atomicAdd(&acc[d0 * D + k],      w0 * __uint_as_float(p0 << 16));
            atomicAdd(&acc[d0 * D + 32 + k], w0 * __uint_as_float(p0 & 0xFFFF0000u));
            atomicAdd(&acc[d1 * D + k],      w1 * __uint_as_float(p1 << 16));
            atomicAdd(&acc[d1 * D + 32 + k], w1 * __uint_as_float(p1 & 0xFFFF0000u));
        }
        if (j < nb) {
            int2 a0 = ebuf[j];
            unsigned p0 = projW[(size_t)(a0.x & 0xFFFFF) * 32 + k];
            float w0 = __int_as_float(a0.y);
            int d0 = ((unsigned)a0.x) >> 20;
            atomicAdd(&acc[d0 * D + k],      w0 * __uint_as_float(p0 << 16));
            atomicAdd(&acc[d0 * D + 32 + k], w0 * __uint_as_float(p0 & 0xFFFF0000u));
        }
        __syncthreads();
    }

    if (sOvf > 0) {                      // insurance path, never hot
        for (int e = hw; e < sOvf; e += 16) {
            int4 o = ovf[e];
            if (o.z != b) continue;
            int dL = ((unsigned)o.x) >> 20;
            float wgt = __int_as_float(o.y);
            unsigned p = projW[(size_t)(o.x & 0xFFFFF) * 32 + k];
            atomicAdd(&acc[dL * D + k],      wgt * __uint_as_float(p << 16));
            atomicAdd(&acc[dL * D + 32 + k], wgt * __uint_as_float(p & 0xFFFF0000u));
        }
        __syncthreads();
    }

    // coalesced writeout: 2048 float4s
    int node0 = b * NPB;
#pragma unroll
    for (int i = 0; i < (NPB * D / 4) / GT; ++i) {
        int f4 = t + i * GT;
        int node = node0 + (f4 >> 4);
        if (node < N)
            *(float4*)&out[(size_t)node0 * D + (size_t)f4 * 4] = ((float4*)acc)[f4];
    }
}

// ---------------------------------------------------------------------------
// Tiled row GEMM -> bf16 packed proj (PAIRED layout: word j of a row holds
// (bf16 col j, bf16 col j+32) so gather lane k gets dims {k, k+32} in one
// word). Block = 64 rows; A staged transposed in LDS; theta in LDS; thread
// computes 4 rows x cols {cw, cw+1, cw+32, cw+33}, cw = (t&15)*2.
// __launch_bounds__(256,4): cap VGPR at 128 (r5 post-mortem: 252 VGPR, 9%
// occupancy without it). unroll 16 keeps ILP within the cap.
// ---------------------------------------------------------------------------
__global__ __launch_bounds__(256, 4) void rowgemm_bf16_kernel(const float* __restrict__ A,
                                                              const float* __restrict__ theta,
                                                              unsigned* __restrict__ projW,
                                                              int N) {
    __shared__ float th[D * D];
    __shared__ float at[D][68];
    int t = threadIdx.x;
    int rowBase = blockIdx.x * 64;

#pragma unroll
    for (int i = 0; i < 4; ++i) {
        int f = t + i * 256;
        ((float4*)th)[f] = ((const float4*)theta)[f];
    }
#pragma unroll
    for (int i = 0; i < 4; ++i) {
        int f = t + i * 256;
        int row = f >> 4;
        int kv = f & 15;
        float4 v = make_float4(0.f, 0.f, 0.f, 0.f);
        if (rowBase + row < N) v = *(const float4*)&A[(size_t)(rowBase + row) * D + kv * 4];
        at[kv * 4 + 0][row] = v.x;
        at[kv * 4 + 1][row] = v.y;
        at[kv * 4 + 2][row] = v.z;
        at[kv * 4 + 3][row] = v.w;
    }
    __syncthreads();

    int cw = (t & 15) * 2;          // word-cols {cw, cw+1} -> cols {cw,cw+1,cw+32,cw+33}
    int r0 = (t >> 4) * 4;
    float4 acc0 = make_float4(0.f, 0.f, 0.f, 0.f);
    float4 acc1 = acc0, acc2 = acc0, acc3 = acc0;

#pragma unroll 16
    for (int k = 0; k < D; ++k) {
        float2 bl = *(const float2*)&th[k * D + cw];
        float2 bh = *(const float2*)&th[k * D + cw + 32];
        float4 bv = make_float4(bl.x, bl.y, bh.x, bh.y);
        float4 av = *(const float4*)&at[k][r0];
        acc0.x += av.x * bv.x; acc0.y += av.x * bv.y; acc0.z += av.x * bv.z; acc0.w += av.x * bv.w;
        acc1.x += av.y * bv.x; acc1.y += av.y * bv.y; acc1.z += av.y * bv.z; acc1.w += av.y * bv.w;
        acc2.x += av.z * bv.x; acc2.y += av.z * bv.y; acc2.z += av.z * bv.z; acc2.w += av.z * bv.w;
        acc3.x += av.w * bv.x; acc3.y += av.w * bv.y; acc3.z += av.w * bv.z; acc3.w += av.w * bv.w;
    }

    float4 accs[4] = {acc0, acc1, acc2, acc3};
#pragma unroll
    for (int i = 0; i < 4; ++i) {
        int r = rowBase + r0 + i;
        if (r < N) {
            // word cw   = (col cw,   col cw+32); word cw+1 = (col cw+1, col cw+33)
            unsigned wa = f2bf(accs[i].x) | (f2bf(accs[i].z) << 16);
            unsigned wb = f2bf(accs[i].y) | (f2bf(accs[i].w) << 16);
            *(uint2*)&projW[(size_t)r * 32 + cw] = make_uint2(wa, wb);
        }
    }
}

// ---------------------------------------------------------------------------
// fallback path (atomic scatter + fp32 row GEMM) if ws/shape checks fail
// ---------------------------------------------------------------------------
__global__ void scatter_kernel(const int* __restrict__ src, const int* __restrict__ dst,
                               const float* __restrict__ w, const float* __restrict__ data,
                               float* __restrict__ agg, int E) {
    int tid = blockIdx.x * blockDim.x + threadIdx.x;
    int e = tid >> 6;
    int d = tid & 63;
    if (e >= E) return;
    float val = w[e] * data[(size_t)src[e] * D + d];
    atomicAdd(&agg[(size_t)dst[e] * D + d], val);
}

__global__ __launch_bounds__(256, 4) void rowgemm_f32_kernel(const float* __restrict__ A,
                                                             const float* __restrict__ theta,
                                                             float* __restrict__ out, int N) {
    __shared__ float th[D * D];
    __shared__ float at[D][68];
    int t = threadIdx.x;
    int rowBase = blockIdx.x * 64;
#pragma unroll
    for (int i = 0; i < 4; ++i) {
        int f = t + i * 256;
        ((float4*)th)[f] = ((const float4*)theta)[f];
    }
#pragma unroll
    for (int i = 0; i < 4; ++i) {
        int f = t + i * 256;
        int row = f >> 4;
        int kv = f & 15;
        float4 v = make_float4(0.f, 0.f, 0.f, 0.f);
        if (rowBase + row < N) v = *(const float4*)&A[(size_t)(rowBase + row) * D + kv * 4];
        at[kv * 4 + 0][row] = v.x;
        at[kv * 4 + 1][row] = v.y;
        at[kv * 4 + 2][row] = v.z;
        at[kv * 4 + 3][row] = v.w;
    }
    __syncthreads();
    int c0 = (t & 15) * 4;
    int r0 = (t >> 4) * 4;
    float4 acc0 = make_float4(0.f, 0.f, 0.f, 0.f);
    float4 acc1 = acc0, acc2 = acc0, acc3 = acc0;
#pragma unroll 16
    for (int kk = 0; kk < D; ++kk) {
        float4 bv = *(const float4*)&th[kk * D + c0];
        float4 av = *(const float4*)&at[kk][r0];
        acc0.x += av.x * bv.x; acc0.y += av.x * bv.y; acc0.z += av.x * bv.z; acc0.w += av.x * bv.w;
        acc1.x += av.y * bv.x; acc1.y += av.y * bv.y; acc1.z += av.y * bv.z; acc1.w += av.y * bv.w;
        acc2.x += av.z * bv.x; acc2.y += av.z * bv.y; acc2.z += av.z * bv.z; acc2.w += av.z * bv.w;
        acc3.x += av.w * bv.x; acc3.y += av.w * bv.y; acc3.z += av.w * bv.z; acc3.w += av.w * bv.w;
    }
    float4 accs[4] = {acc0, acc1, acc2, acc3};
#pragma unroll
    for (int i = 0; i < 4; ++i) {
        int r = rowBase + r0 + i;
        if (r < N) *(float4*)&out[(size_t)r * D + c0] = accs[i];
    }
}

extern "C" void kernel_launch(void* const* d_in, const int* in_sizes, int n_in,
                              void* d_out, int out_size, void* d_ws, size_t ws_size,
                              hipStream_t stream) {
    const int*   src   = (const int*)d_in[0];
    const int*   dst   = (const int*)d_in[1];
    const float* w     = (const float*)d_in[2];
    const float* data  = (const float*)d_in[3];
    const float* theta = (const float*)d_in[4];
    const int E = in_sizes[0];
    const int N = in_sizes[3] / D;
    float* out = (float*)d_out;

    const int B = (N + NPB - 1) / NPB;

    // ws layout: proj16 (bf16, paired words) | adjB (B*CAPB int2) |
    //            ovf (E int4) | cursor[B] | ovfCnt
    size_t projBytes = (size_t)N * D * 2;
    size_t adjBytes  = (size_t)B * CAPB * 8;
    size_t ovfBytes  = (size_t)E * 16;
    size_t need = projBytes + adjBytes + ovfBytes + ((size_t)B + 1) * 4 + 256;

    if (ws_size >= need && N < (1 << 20) && B <= MAXB) {
        unsigned* projW = (unsigned*)d_ws;
        int2* adjB   = (int2*)((char*)d_ws + projBytes);
        int4* ovf    = (int4*)((char*)d_ws + projBytes + adjBytes);
        int*  cursor = (int*)((char*)d_ws + projBytes + adjBytes + ovfBytes);
        int*  ovfCnt = cursor + B;

        int gs = (E + CHUNK_MAX - 1) / CHUNK_MAX;  // chunk <= CHUNK_MAX

        zero_i_kernel<<<(B + 1 + 255) / 256, 256, 0, stream>>>(cursor, B + 1);
        bucket_scatter_kernel<<<gs, SCATTER_T, 0, stream>>>(src, dst, w, cursor,
                                                            ovfCnt, ovf, adjB, E, B);
        rowgemm_bf16_kernel<<<(N + 63) / 64, 256, 0, stream>>>(data, theta, projW, N);
        accum_gather_kernel<<<B, GT, 0, stream>>>(adjB, cursor, ovfCnt, ovf,
                                                  projW, out, N);
    } else {
        float* agg = (float*)d_ws;
        int n4 = (N * D) / 4;
        zero_f4_kernel<<<(n4 + 255) / 256, 256, 0, stream>>>((float4*)agg, n4);
        long long total = (long long)E * D;
        scatter_kernel<<<(int)((total + 255) / 256), 256, 0, stream>>>(src, dst, w, data, agg, E);
        rowgemm_f32_kernel<<<(N + 63) / 64, 256, 0, stream>>>(agg, theta, out, N);
    }
}

// Round 6
// 628.420 us; speedup vs baseline: 1.0030x; 1.0030x over previous
//
#include <hip/hip_runtime.h>

#define D 64
#define NPB 128              // nodes per bucket (dstLocal: 7 bits)
#define NPB_SHIFT 7
#define MAXB 1024            // bound on bucket count B = ceil(N/NPB)
#define SCATTER_T 512
#define CHUNK_MAX 4704       // max edges staged per scatter block (LDS-sized)
#define SCQ 10               // per-thread reg-staged edges (SCQ*512 >= CHUNK_MAX)
#define CAPB 2560            // fixed per-bucket capacity in adjB (mean 1534)
#define GT 512               // accum_gather block size (8 waves)

// round-to-nearest-even fp32 -> bf16 (values are finite/normal here)
__device__ inline unsigned f2bf(float f) {
    unsigned u = __float_as_uint(f);
    return (u + 0x7FFFu + ((u >> 16) & 1u)) >> 16;
}

// Native fire-and-forget LDS float add. HIP's atomicAdd on LDS f32 lowers to
// a CAS loop (r5 post-mortem: 519us, VALUBusy 2%, all pipes idle — serial
// ds_read/ds_cmpst chains + retry storms). ds_add_f32 is single-issue,
// no-return, no-retry. Generic LDS pointers carry the LDS byte offset in
// their low 32 bits (apertures are 2^32-aligned), so truncation is the vaddr.
__device__ inline void ldsAddF32(float* p, float v) {
    asm volatile("ds_add_f32 %0, %1"
                 :: "v"((unsigned)(uintptr_t)p), "v"(v) : "memory");
}

// ---------------------------------------------------------------------------
// zero helpers (ws is poisoned 0xAA every launch)
// ---------------------------------------------------------------------------
__global__ void zero_i_kernel(int* __restrict__ p, int n) {
    int i = blockIdx.x * blockDim.x + threadIdx.x;
    if (i < n) p[i] = 0;
}
__global__ void zero_f4_kernel(float4* __restrict__ p, int n4) {
    int i = blockIdx.x * blockDim.x + threadIdx.x;
    if (i < n4) p[i] = make_float4(0.f, 0.f, 0.f, 0.f);
}

// ---------------------------------------------------------------------------
// bucket scatter (unchanged from r5): reg-stage edges -> LDS chunk histogram
// -> local excl scan -> reserve per-bucket ranges -> LDS counting sort ->
// coalesced write-out in ~48B runs. Overflow past CAPB -> ovf list (cold).
// Packing: x = src | dstLocal<<20, y = w bits.
// ---------------------------------------------------------------------------
__global__ __launch_bounds__(SCATTER_T) void bucket_scatter_kernel(
        const int* __restrict__ src, const int* __restrict__ dst,
        const float* __restrict__ w, int* __restrict__ cursor,
        int* __restrict__ ovfCnt, int4* __restrict__ ovf,
        int2* __restrict__ adjB, int E, int B) {
    __shared__ int lc[MAXB];
    __shared__ int lpre[MAXB];
    __shared__ int lbase[MAXB];
    __shared__ int lfill[MAXB];
    __shared__ int sums[SCATTER_T];
    __shared__ unsigned short sb[CHUNK_MAX];
    __shared__ int2 stage[CHUNK_MAX];

    int t = threadIdx.x;
    int chunk = (E + gridDim.x - 1) / gridDim.x;   // <= CHUNK_MAX by host calc
    int lo = blockIdx.x * chunk, hi = min(lo + chunk, E);
    int n = hi - lo;
    if (n <= 0) return;

    for (int i = t; i < MAXB; i += SCATTER_T) { lc[i] = 0; lfill[i] = 0; }

    // reg-stage this thread's edges (one global pass over dst/src/w)
    int rd[SCQ]; int rs[SCQ]; float rw[SCQ];
#pragma unroll
    for (int q = 0; q < SCQ; ++q) {
        int e = lo + t + q * SCATTER_T;
        bool v = e < hi;
        rd[q] = v ? dst[e] : -1;
        rs[q] = v ? src[e] : 0;
        rw[q] = v ? w[e] : 0.f;
    }
    __syncthreads();

    // A1: chunk histogram
#pragma unroll
    for (int q = 0; q < SCQ; ++q)
        if (rd[q] >= 0) atomicAdd(&lc[rd[q] >> NPB_SHIFT], 1);
    __syncthreads();

    // A2: exclusive scan of lc[0..MAXB) (2/thread + H-S on 512)
    int s0 = lc[2 * t], s1 = lc[2 * t + 1];
    sums[t] = s0 + s1;
    __syncthreads();
    for (int st = 1; st < SCATTER_T; st <<= 1) {
        int v = (t >= st) ? sums[t - st] : 0;
        __syncthreads();
        sums[t] += v;
        __syncthreads();
    }
    int ex = (t == 0) ? 0 : sums[t - 1];
    lpre[2 * t] = ex;
    lpre[2 * t + 1] = ex + s0;
    __syncthreads();

    // A3: reserve per-bucket ranges (1 global atomic per nonempty bucket)
    for (int i = t; i < B; i += SCATTER_T) {
        int c = lc[i];
        lbase[i] = c ? atomicAdd(&cursor[i], c) : 0;
    }
    __syncthreads();

    // B: place into locally-sorted LDS slots
#pragma unroll
    for (int q = 0; q < SCQ; ++q) {
        int d = rd[q];
        if (d >= 0) {
            int bkt = d >> NPB_SHIFT;
            int i = lpre[bkt] + atomicAdd(&lfill[bkt], 1);
            stage[i] = make_int2(rs[q] | ((d & (NPB - 1)) << 20),
                                 __float_as_int(rw[q]));
            sb[i] = (unsigned short)bkt;
        }
    }
    __syncthreads();

    // C: coalesced write-out in locally-sorted order
    for (int i = t; i < n; i += SCATTER_T) {
        int bkt = sb[i];
        int2 v = stage[i];
        int pos = lbase[bkt] + (i - lpre[bkt]);
        if (pos < CAPB) {
            adjB[(size_t)bkt * CAPB + pos] = v;
        } else {                               // cold: bucket overflow
            int oi = atomicAdd(ovfCnt, 1);
            ovf[oi] = make_int4(v.x, v.y, bkt, 0);
        }
    }
}

// ---------------------------------------------------------------------------
// accum gather v2: one block per bucket, NO sorting. Stream the bucket's
// adjB slice (staged 512 edges/chunk into LDS); each HALF-WAVE takes 4 edges
// in flight, reads their 128B proj rows, and ds_add_f32's into acc[node].
// Mapping: lane k owns dims {k, k+32}; proj word j packs (col j, col j+32),
// so every LDS add hits bank k -> exactly 2 lanes/bank per wave64 (free),
// independent of which nodes the halves process. No-return native atomics
// -> no CAS, no waits; round cost = proj load latency, 4-deep MLP.
// Final: barrier + coalesced float4 writeout. LDS 36.3KB -> 4 blocks/CU.
// ---------------------------------------------------------------------------
__global__ __launch_bounds__(GT) void accum_gather_kernel(
        const int2* __restrict__ adjB, const int* __restrict__ cursor,
        const int* __restrict__ ovfCnt, const int4* __restrict__ ovf,
        const unsigned* __restrict__ projW, float* __restrict__ out, int N) {
    __shared__ float acc[NPB * D];       // 32 KB
    __shared__ int2 ebuf[GT];            // 4 KB
    __shared__ int sOvf;

    int b = blockIdx.x;
    int t = threadIdx.x;
    int m = min(cursor[b], CAPB);
    const int2* base = adjB + (size_t)b * CAPB;

#pragma unroll
    for (int i = 0; i < (NPB * D / 4) / GT; ++i)
        ((float4*)acc)[t + i * GT] = make_float4(0.f, 0.f, 0.f, 0.f);
    if (t == 0) sOvf = *ovfCnt;
    __syncthreads();

    int hw = t >> 5;        // half-wave 0..15
    int k = t & 31;         // lane owns dims {k, k+32}

    for (int base_e = 0; base_e < m; base_e += GT) {
        int nb = min(GT, m - base_e);
        if (base_e + t < m) ebuf[t] = base[base_e + t];
        __syncthreads();
        int j = hw;
        for (; j + 48 < nb; j += 64) {   // 4 edges / proj loads in flight
            int2 a0 = ebuf[j];
            int2 a1 = ebuf[j + 16];
            int2 a2 = ebuf[j + 32];
            int2 a3 = ebuf[j + 48];
            unsigned p0 = projW[(size_t)(a0.x & 0xFFFFF) * 32 + k];
            unsigned p1 = projW[(size_t)(a1.x & 0xFFFFF) * 32 + k];
            unsigned p2 = projW[(size_t)(a2.x & 0xFFFFF) * 32 + k];
            unsigned p3 = projW[(size_t)(a3.x & 0xFFFFF) * 32 + k];
            float w0 = __int_as_float(a0.y), w1 = __int_as_float(a1.y);
            float w2 = __int_as_float(a2.y), w3 = __int_as_float(a3.y);
            int d0 = ((unsigned)a0.x) >> 20, d1 = ((unsigned)a1.x) >> 20;
            int d2 = ((unsigned)a2.x) >> 20, d3 = ((unsigned)a3.x) >> 20;
            ldsAddF32(&acc[d0 * D + k],      w0 * __uint_as_float(p0 << 16));
            ldsAddF32(&acc[d0 * D + 32 + k], w0 * __uint_as_float(p0 & 0xFFFF0000u));
            ldsAddF32(&acc[d1 * D + k],      w1 * __uint_as_float(p1 << 16));
            ldsAddF32(&acc[d1 * D + 32 + k], w1 * __uint_as_float(p1 & 0xFFFF0000u));
            ldsAddF32(&acc[d2 * D + k],      w2 * __uint_as_float(p2 << 16));
            ldsAddF32(&acc[d2 * D + 32 + k], w2 * __uint_as_float(p2 & 0xFFFF0000u));
            ldsAddF32(&acc[d3 * D + k],      w3 * __uint_as_float(p3 << 16));
            ldsAddF32(&acc[d3 * D + 32 + k], w3 * __uint_as_float(p3 & 0xFFFF0000u));
        }
        for (; j < nb; j += 16) {        // tail, one edge at a time
            int2 a0 = ebuf[j];
            unsigned p0 = projW[(size_t)(a0.x & 0xFFFFF) * 32 + k];
            float w0 = __int_as_float(a0.y);
            int d0 = ((unsigned)a0.x) >> 20;
            ldsAddF32(&acc[d0 * D + k],      w0 * __uint_as_float(p0 << 16));
            ldsAddF32(&acc[d0 * D + 32 + k], w0 * __uint_as_float(p0 & 0xFFFF0000u));
        }
        __syncthreads();
    }

    if (sOvf > 0) {                      // insurance path, never hot
        for (int e = hw; e < sOvf; e += 16) {
            int4 o = ovf[e];
            if (o.z != b) continue;
            int dL = ((unsigned)o.x) >> 20;
            float wgt = __int_as_float(o.y);
            unsigned p = projW[(size_t)(o.x & 0xFFFFF) * 32 + k];
            ldsAddF32(&acc[dL * D + k],      wgt * __uint_as_float(p << 16));
            ldsAddF32(&acc[dL * D + 32 + k], wgt * __uint_as_float(p & 0xFFFF0000u));
        }
        __syncthreads();
    }

    // coalesced writeout: 2048 float4s
    int node0 = b * NPB;
#pragma unroll
    for (int i = 0; i < (NPB * D / 4) / GT; ++i) {
        int f4 = t + i * GT;
        int node = node0 + (f4 >> 4);
        if (node < N)
            *(float4*)&out[(size_t)node0 * D + (size_t)f4 * 4] = ((float4*)acc)[f4];
    }
}

// ---------------------------------------------------------------------------
// Tiled row GEMM -> bf16 packed proj (PAIRED layout: word j of a row holds
// (bf16 col j, bf16 col j+32) so gather lane k gets dims {k, k+32} in one
// word). Block = 64 rows; A staged transposed in LDS; theta in LDS; thread
// computes 4 rows x cols {cw, cw+1, cw+32, cw+33}, cw = (t&15)*2.
// __launch_bounds__(256,4): cap VGPR at 128. unroll 16 keeps ILP in cap.
// ---------------------------------------------------------------------------
__global__ __launch_bounds__(256, 4) void rowgemm_bf16_kernel(const float* __restrict__ A,
                                                              const float* __restrict__ theta,
                                                              unsigned* __restrict__ projW,
                                                              int N) {
    __shared__ float th[D * D];
    __shared__ float at[D][68];
    int t = threadIdx.x;
    int rowBase = blockIdx.x * 64;

#pragma unroll
    for (int i = 0; i < 4; ++i) {
        int f = t + i * 256;
        ((float4*)th)[f] = ((const float4*)theta)[f];
    }
#pragma unroll
    for (int i = 0; i < 4; ++i) {
        int f = t + i * 256;
        int row = f >> 4;
        int kv = f & 15;
        float4 v = make_float4(0.f, 0.f, 0.f, 0.f);
        if (rowBase + row < N) v = *(const float4*)&A[(size_t)(rowBase + row) * D + kv * 4];
        at[kv * 4 + 0][row] = v.x;
        at[kv * 4 + 1][row] = v.y;
        at[kv * 4 + 2][row] = v.z;
        at[kv * 4 + 3][row] = v.w;
    }
    __syncthreads();

    int cw = (t & 15) * 2;          // word-cols {cw, cw+1} -> cols {cw,cw+1,cw+32,cw+33}
    int r0 = (t >> 4) * 4;
    float4 acc0 = make_float4(0.f, 0.f, 0.f, 0.f);
    float4 acc1 = acc0, acc2 = acc0, acc3 = acc0;

#pragma unroll 16
    for (int k = 0; k < D; ++k) {
        float2 bl = *(const float2*)&th[k * D + cw];
        float2 bh = *(const float2*)&th[k * D + cw + 32];
        float4 bv = make_float4(bl.x, bl.y, bh.x, bh.y);
        float4 av = *(const float4*)&at[k][r0];
        acc0.x += av.x * bv.x; acc0.y += av.x * bv.y; acc0.z += av.x * bv.z; acc0.w += av.x * bv.w;
        acc1.x += av.y * bv.x; acc1.y += av.y * bv.y; acc1.z += av.y * bv.z; acc1.w += av.y * bv.w;
        acc2.x += av.z * bv.x; acc2.y += av.z * bv.y; acc2.z += av.z * bv.z; acc2.w += av.z * bv.w;
        acc3.x += av.w * bv.x; acc3.y += av.w * bv.y; acc3.z += av.w * bv.z; acc3.w += av.w * bv.w;
    }

    float4 accs[4] = {acc0, acc1, acc2, acc3};
#pragma unroll
    for (int i = 0; i < 4; ++i) {
        int r = rowBase + r0 + i;
        if (r < N) {
            // word cw   = (col cw,   col cw+32); word cw+1 = (col cw+1, col cw+33)
            unsigned wa = f2bf(accs[i].x) | (f2bf(accs[i].z) << 16);
            unsigned wb = f2bf(accs[i].y) | (f2bf(accs[i].w) << 16);
            *(uint2*)&projW[(size_t)r * 32 + cw] = make_uint2(wa, wb);
        }
    }
}

// ---------------------------------------------------------------------------
// fallback path (atomic scatter + fp32 row GEMM) if ws/shape checks fail
// ---------------------------------------------------------------------------
__global__ void scatter_kernel(const int* __restrict__ src, const int* __restrict__ dst,
                               const float* __restrict__ w, const float* __restrict__ data,
                               float* __restrict__ agg, int E) {
    int tid = blockIdx.x * blockDim.x + threadIdx.x;
    int e = tid >> 6;
    int d = tid & 63;
    if (e >= E) return;
    float val = w[e] * data[(size_t)src[e] * D + d];
    atomicAdd(&agg[(size_t)dst[e] * D + d], val);
}

__global__ __launch_bounds__(256, 4) void rowgemm_f32_kernel(const float* __restrict__ A,
                                                             const float* __restrict__ theta,
                                                             float* __restrict__ out, int N) {
    __shared__ float th[D * D];
    __shared__ float at[D][68];
    int t = threadIdx.x;
    int rowBase = blockIdx.x * 64;
#pragma unroll
    for (int i = 0; i < 4; ++i) {
        int f = t + i * 256;
        ((float4*)th)[f] = ((const float4*)theta)[f];
    }
#pragma unroll
    for (int i = 0; i < 4; ++i) {
        int f = t + i * 256;
        int row = f >> 4;
        int kv = f & 15;
        float4 v = make_float4(0.f, 0.f, 0.f, 0.f);
        if (rowBase + row < N) v = *(const float4*)&A[(size_t)(rowBase + row) * D + kv * 4];
        at[kv * 4 + 0][row] = v.x;
        at[kv * 4 + 1][row] = v.y;
        at[kv * 4 + 2][row] = v.z;
        at[kv * 4 + 3][row] = v.w;
    }
    __syncthreads();
    int c0 = (t & 15) * 4;
    int r0 = (t >> 4) * 4;
    float4 acc0 = make_float4(0.f, 0.f, 0.f, 0.f);
    float4 acc1 = acc0, acc2 = acc0, acc3 = acc0;
#pragma unroll 16
    for (int kk = 0; kk < D; ++kk) {
        float4 bv = *(const float4*)&th[kk * D + c0];
        float4 av = *(const float4*)&at[kk][r0];
        acc0.x += av.x * bv.x; acc0.y += av.x * bv.y; acc0.z += av.x * bv.z; acc0.w += av.x * bv.w;
        acc1.x += av.y * bv.x; acc1.y += av.y * bv.y; acc1.z += av.y * bv.z; acc1.w += av.y * bv.w;
        acc2.x += av.z * bv.x; acc2.y += av.z * bv.y; acc2.z += av.z * bv.z; acc2.w += av.z * bv.w;
        acc3.x += av.w * bv.x; acc3.y += av.w * bv.y; acc3.z += av.w * bv.z; acc3.w += av.w * bv.w;
    }
    float4 accs[4] = {acc0, acc1, acc2, acc3};
#pragma unroll
    for (int i = 0; i < 4; ++i) {
        int r = rowBase + r0 + i;
        if (r < N) *(float4*)&out[(size_t)r * D + c0] = accs[i];
    }
}

extern "C" void kernel_launch(void* const* d_in, const int* in_sizes, int n_in,
                              void* d_out, int out_size, void* d_ws, size_t ws_size,
                              hipStream_t stream) {
    const int*   src   = (const int*)d_in[0];
    const int*   dst   = (const int*)d_in[1];
    const float* w     = (const float*)d_in[2];
    const float* data  = (const float*)d_in[3];
    const float* theta = (const float*)d_in[4];
    const int E = in_sizes[0];
    const int N = in_sizes[3] / D;
    float* out = (float*)d_out;

    const int B = (N + NPB - 1) / NPB;

    // ws layout: proj16 (bf16, paired words) | adjB (B*CAPB int2) |
    //            ovf (E int4) | cursor[B] | ovfCnt
    size_t projBytes = (size_t)N * D * 2;
    size_t adjBytes  = (size_t)B * CAPB * 8;
    size_t ovfBytes  = (size_t)E * 16;
    size_t need = projBytes + adjBytes + ovfBytes + ((size_t)B + 1) * 4 + 256;

    if (ws_size >= need && N < (1 << 20) && B <= MAXB) {
        unsigned* projW = (unsigned*)d_ws;
        int2* adjB   = (int2*)((char*)d_ws + projBytes);
        int4* ovf    = (int4*)((char*)d_ws + projBytes + adjBytes);
        int*  cursor = (int*)((char*)d_ws + projBytes + adjBytes + ovfBytes);
        int*  ovfCnt = cursor + B;

        int gs = (E + CHUNK_MAX - 1) / CHUNK_MAX;  // chunk <= CHUNK_MAX

        zero_i_kernel<<<(B + 1 + 255) / 256, 256, 0, stream>>>(cursor, B + 1);
        bucket_scatter_kernel<<<gs, SCATTER_T, 0, stream>>>(src, dst, w, cursor,
                                                            ovfCnt, ovf, adjB, E, B);
        rowgemm_bf16_kernel<<<(N + 63) / 64, 256, 0, stream>>>(data, theta, projW, N);
        accum_gather_kernel<<<B, GT, 0, stream>>>(adjB, cursor, ovfCnt, ovf,
                                                  projW, out, N);
    } else {
        float* agg = (float*)d_ws;
        int n4 = (N * D) / 4;
        zero_f4_kernel<<<(n4 + 255) / 256, 256, 0, stream>>>((float4*)agg, n4);
        long long total = (long long)E * D;
        scatter_kernel<<<(int)((total + 255) / 256), 256, 0, stream>>>(src, dst, w, data, agg, E);
        rowgemm_f32_kernel<<<(N + 63) / 64, 256, 0, stream>>>(agg, theta, out, N);
    }
}

// Round 7
// 146.127 us; speedup vs baseline: 4.3132x; 4.3005x over previous
//
#include <hip/hip_runtime.h>

#define D 64
#define NPB 128              // nodes per bucket (dstLocal: 7 bits)
#define NPB_SHIFT 7
#define MAXB 1024            // bound on bucket count B = ceil(N/NPB)
#define SCATTER_T 512
#define CHUNK_MAX 4704       // max edges staged per scatter block (LDS-sized)
#define SCQ 10               // per-thread reg-staged edges (SCQ*512 >= CHUNK_MAX)
#define CAPB 2560            // fixed per-bucket capacity in adjB (mean 1534)
#define GT 512               // sort_gather block size (8 waves)
#define GQ 5                 // per-thread reg-staged bucket entries (GQ*GT >= CAPB)

// round-to-nearest-even fp32 -> bf16 (values are finite/normal here)
__device__ inline unsigned f2bf(float f) {
    unsigned u = __float_as_uint(f);
    return (u + 0x7FFFu + ((u >> 16) & 1u)) >> 16;
}

// ---------------------------------------------------------------------------
// zero helpers (ws is poisoned 0xAA every launch)
// ---------------------------------------------------------------------------
__global__ void zero_i_kernel(int* __restrict__ p, int n) {
    int i = blockIdx.x * blockDim.x + threadIdx.x;
    if (i < n) p[i] = 0;
}
__global__ void zero_f4_kernel(float4* __restrict__ p, int n4) {
    int i = blockIdx.x * blockDim.x + threadIdx.x;
    if (i < n4) p[i] = make_float4(0.f, 0.f, 0.f, 0.f);
}

// ---------------------------------------------------------------------------
// bucket scatter (r5-proven): reg-stage edges -> LDS chunk histogram ->
// local excl scan -> reserve per-bucket ranges from cursors -> LDS counting
// sort -> coalesced write-out in ~48B runs. Overflow past CAPB -> ovf (cold).
// Packing: x = src | dstLocal<<20, y = w bits.
// ---------------------------------------------------------------------------
__global__ __launch_bounds__(SCATTER_T) void bucket_scatter_kernel(
        const int* __restrict__ src, const int* __restrict__ dst,
        const float* __restrict__ w, int* __restrict__ cursor,
        int* __restrict__ ovfCnt, int4* __restrict__ ovf,
        int2* __restrict__ adjB, int E, int B) {
    __shared__ int lc[MAXB];
    __shared__ int lpre[MAXB];
    __shared__ int lbase[MAXB];
    __shared__ int lfill[MAXB];
    __shared__ int sums[SCATTER_T];
    __shared__ unsigned short sb[CHUNK_MAX];
    __shared__ int2 stage[CHUNK_MAX];

    int t = threadIdx.x;
    int chunk = (E + gridDim.x - 1) / gridDim.x;   // <= CHUNK_MAX by host calc
    int lo = blockIdx.x * chunk, hi = min(lo + chunk, E);
    int n = hi - lo;
    if (n <= 0) return;

    for (int i = t; i < MAXB; i += SCATTER_T) { lc[i] = 0; lfill[i] = 0; }

    // reg-stage this thread's edges (one global pass over dst/src/w)
    int rd[SCQ]; int rs[SCQ]; float rw[SCQ];
#pragma unroll
    for (int q = 0; q < SCQ; ++q) {
        int e = lo + t + q * SCATTER_T;
        bool v = e < hi;
        rd[q] = v ? dst[e] : -1;
        rs[q] = v ? src[e] : 0;
        rw[q] = v ? w[e] : 0.f;
    }
    __syncthreads();

    // A1: chunk histogram
#pragma unroll
    for (int q = 0; q < SCQ; ++q)
        if (rd[q] >= 0) atomicAdd(&lc[rd[q] >> NPB_SHIFT], 1);
    __syncthreads();

    // A2: exclusive scan of lc[0..MAXB) (2/thread + H-S on 512)
    int s0 = lc[2 * t], s1 = lc[2 * t + 1];
    sums[t] = s0 + s1;
    __syncthreads();
    for (int st = 1; st < SCATTER_T; st <<= 1) {
        int v = (t >= st) ? sums[t - st] : 0;
        __syncthreads();
        sums[t] += v;
        __syncthreads();
    }
    int ex = (t == 0) ? 0 : sums[t - 1];
    lpre[2 * t] = ex;
    lpre[2 * t + 1] = ex + s0;
    __syncthreads();

    // A3: reserve per-bucket ranges (1 global atomic per nonempty bucket)
    for (int i = t; i < B; i += SCATTER_T) {
        int c = lc[i];
        lbase[i] = c ? atomicAdd(&cursor[i], c) : 0;
    }
    __syncthreads();

    // B: place into locally-sorted LDS slots
#pragma unroll
    for (int q = 0; q < SCQ; ++q) {
        int d = rd[q];
        if (d >= 0) {
            int bkt = d >> NPB_SHIFT;
            int i = lpre[bkt] + atomicAdd(&lfill[bkt], 1);
            stage[i] = make_int2(rs[q] | ((d & (NPB - 1)) << 20),
                                 __float_as_int(rw[q]));
            sb[i] = (unsigned short)bkt;
        }
    }
    __syncthreads();

    // C: coalesced write-out in locally-sorted order
    for (int i = t; i < n; i += SCATTER_T) {
        int bkt = sb[i];
        int2 v = stage[i];
        int pos = lbase[bkt] + (i - lpre[bkt]);
        if (pos < CAPB) {
            adjB[(size_t)bkt * CAPB + pos] = v;
        } else {                               // cold: bucket overflow
            int oi = atomicAdd(ovfCnt, 1);
            ovf[oi] = make_int4(v.x, v.y, bkt, 0);
        }
    }
}

// ---------------------------------------------------------------------------
// fused sort+gather (r3-proven): one block per bucket. Single global pass
// stages the bucket's adjB slice into registers while counting; after the
// scan each thread places its staged entries node-grouped into LDS. Gather:
// each HALF-WAVE owns a node (4-deep edge ILP -> 8 proj loads in flight per
// wave), adjacency via LDS broadcast, proj rows 128B/half from L2/L3, own
// 256B row store per half. REGISTER accumulation — r5/r6 lesson: streaming
// LDS-atomic accumulate is ~10x slower regardless of atomic flavor.
// Overflow entries (cursor > CAPB, never for this input) drained with
// global float atomics after the block's own stores.
// ---------------------------------------------------------------------------
__global__ __launch_bounds__(GT) void sort_gather_kernel(
        const int2* __restrict__ adjB, const int* __restrict__ cursor,
        const int* __restrict__ ovfCnt, const int4* __restrict__ ovf,
        const unsigned* __restrict__ projU, float* __restrict__ out, int N) {
    __shared__ int cnt[NPB];
    __shared__ int pre[NPB];
    __shared__ int fill[NPB];
    __shared__ int2 ladj[CAPB];
    __shared__ int sOvf;

    int b = blockIdx.x;
    int t = threadIdx.x;
    int total = cursor[b];
    int m = min(total, CAPB);
    const int2* base = adjB + (size_t)b * CAPB;

    if (t < NPB) { cnt[t] = 0; fill[t] = 0; }
    if (t == 0) sOvf = *ovfCnt;
    __syncthreads();

    // single global pass: reg-stage + histogram
    int2 r[GQ];
#pragma unroll
    for (int q = 0; q < GQ; ++q) {
        int e = t + q * GT;
        if (e < m) {
            int2 a = base[e];
            r[q] = a;
            atomicAdd(&cnt[((unsigned)a.x) >> 20], 1);
        }
    }
    __syncthreads();
    if (t < NPB) pre[t] = cnt[t];
    __syncthreads();
    for (int st = 1; st < NPB; st <<= 1) {
        int v = (t < NPB && t >= st) ? pre[t - st] : 0;
        __syncthreads();
        if (t < NPB) pre[t] += v;
        __syncthreads();
    }
    // place node-grouped into LDS from registers
#pragma unroll
    for (int q = 0; q < GQ; ++q) {
        int e = t + q * GT;
        if (e < m) {
            int2 a = r[q];
            int dL = ((unsigned)a.x) >> 20;
            int pos = ((dL == 0) ? 0 : pre[dL - 1]) + atomicAdd(&fill[dL], 1);
            ladj[pos] = make_int2(a.x & 0xFFFFF, a.y);
        }
    }
    __syncthreads();

    int wave = t >> 6;          // 0..7
    int lane = t & 63;
    int half = lane >> 5;
    int k = lane & 31;          // lane owns dims {2k, 2k+1} of its half's node

#pragma unroll 1
    for (int i = 0; i < 8; ++i) {            // 2 nodes per wave-iter
        int dL = wave * 16 + i * 2 + half;
        int node = b * NPB + dL;
        if (node < N) {
            int rb = (dL == 0) ? 0 : pre[dL - 1];
            int re = pre[dL];
            float2 accA = make_float2(0.f, 0.f);
            float2 accB = make_float2(0.f, 0.f);
            int j = rb;
            for (; j + 3 < re; j += 4) {     // 4 proj loads in flight per half
                int2 a0 = ladj[j];
                int2 a1 = ladj[j + 1];
                int2 a2 = ladj[j + 2];
                int2 a3 = ladj[j + 3];
                unsigned p0 = projU[(size_t)a0.x * 32 + k];
                unsigned p1 = projU[(size_t)a1.x * 32 + k];
                unsigned p2 = projU[(size_t)a2.x * 32 + k];
                unsigned p3 = projU[(size_t)a3.x * 32 + k];
                float w0 = __int_as_float(a0.y), w1 = __int_as_float(a1.y);
                float w2 = __int_as_float(a2.y), w3 = __int_as_float(a3.y);
                accA.x += w0 * __uint_as_float(p0 << 16);
                accA.y += w0 * __uint_as_float(p0 & 0xFFFF0000u);
                accB.x += w1 * __uint_as_float(p1 << 16);
                accB.y += w1 * __uint_as_float(p1 & 0xFFFF0000u);
                accA.x += w2 * __uint_as_float(p2 << 16);
                accA.y += w2 * __uint_as_float(p2 & 0xFFFF0000u);
                accB.x += w3 * __uint_as_float(p3 << 16);
                accB.y += w3 * __uint_as_float(p3 & 0xFFFF0000u);
            }
            for (; j < re; ++j) {
                int2 a0 = ladj[j];
                float w0 = __int_as_float(a0.y);
                unsigned p0 = projU[(size_t)a0.x * 32 + k];
                accA.x += w0 * __uint_as_float(p0 << 16);
                accA.y += w0 * __uint_as_float(p0 & 0xFFFF0000u);
            }
            float2 acc = make_float2(accA.x + accB.x, accA.y + accB.y);
            *(float2*)&out[(size_t)node * D + 2 * k] = acc;  // 32 lanes x 8B
        }
    }

    if (sOvf > 0) {                           // insurance path, never hot
        __syncthreads();                      // order our stores before atomics
        for (int e = t; e < sOvf; e += GT) {
            int4 o = ovf[e];
            if (o.z != b) continue;
            int dL = ((unsigned)o.x) >> 20;
            int node = b * NPB + dL;
            if (node >= N) continue;
            float wgt = __int_as_float(o.y);
            int s = o.x & 0xFFFFF;
            for (int d2 = 0; d2 < D / 2; ++d2) {
                unsigned p = projU[(size_t)s * 32 + d2];
                atomicAdd(&out[(size_t)node * D + 2 * d2],     wgt * __uint_as_float(p << 16));
                atomicAdd(&out[(size_t)node * D + 2 * d2 + 1], wgt * __uint_as_float(p & 0xFFFF0000u));
            }
        }
    }
}

// ---------------------------------------------------------------------------
// Tiled row GEMM -> bf16 packed proj (r2-proven, adjacent-pair words: word j
// of a row = (bf16 col 2j, bf16 col 2j+1)). Block = 64 rows; A staged
// transposed in LDS; theta in LDS; thread computes 4x4 block.
// __launch_bounds__(256,4): cap VGPR at 128. unroll 16 keeps ILP in cap.
// ---------------------------------------------------------------------------
__global__ __launch_bounds__(256, 4) void rowgemm_bf16_kernel(const float* __restrict__ A,
                                                              const float* __restrict__ theta,
                                                              unsigned short* __restrict__ proj16,
                                                              int N) {
    __shared__ float th[D * D];
    __shared__ float at[D][68];
    int t = threadIdx.x;
    int rowBase = blockIdx.x * 64;

#pragma unroll
    for (int i = 0; i < 4; ++i) {
        int f = t + i * 256;
        ((float4*)th)[f] = ((const float4*)theta)[f];
    }
#pragma unroll
    for (int i = 0; i < 4; ++i) {
        int f = t + i * 256;
        int row = f >> 4;
        int kv = f & 15;
        float4 v = make_float4(0.f, 0.f, 0.f, 0.f);
        if (rowBase + row < N) v = *(const float4*)&A[(size_t)(rowBase + row) * D + kv * 4];
        at[kv * 4 + 0][row] = v.x;
        at[kv * 4 + 1][row] = v.y;
        at[kv * 4 + 2][row] = v.z;
        at[kv * 4 + 3][row] = v.w;
    }
    __syncthreads();

    int c0 = (t & 15) * 4;
    int r0 = (t >> 4) * 4;
    float4 acc0 = make_float4(0.f, 0.f, 0.f, 0.f);
    float4 acc1 = acc0, acc2 = acc0, acc3 = acc0;

#pragma unroll 16
    for (int k = 0; k < D; ++k) {
        float4 bv = *(const float4*)&th[k * D + c0];
        float4 av = *(const float4*)&at[k][r0];
        acc0.x += av.x * bv.x; acc0.y += av.x * bv.y; acc0.z += av.x * bv.z; acc0.w += av.x * bv.w;
        acc1.x += av.y * bv.x; acc1.y += av.y * bv.y; acc1.z += av.y * bv.z; acc1.w += av.y * bv.w;
        acc2.x += av.z * bv.x; acc2.y += av.z * bv.y; acc2.z += av.z * bv.z; acc2.w += av.z * bv.w;
        acc3.x += av.w * bv.x; acc3.y += av.w * bv.y; acc3.z += av.w * bv.z; acc3.w += av.w * bv.w;
    }

    float4 accs[4] = {acc0, acc1, acc2, acc3};
#pragma unroll
    for (int i = 0; i < 4; ++i) {
        int r = rowBase + r0 + i;
        if (r < N) {
            unsigned lo = f2bf(accs[i].x) | (f2bf(accs[i].y) << 16);
            unsigned hi = f2bf(accs[i].z) | (f2bf(accs[i].w) << 16);
            *(uint2*)&proj16[(size_t)r * D + c0] = make_uint2(lo, hi);
        }
    }
}

// ---------------------------------------------------------------------------
// fallback path (atomic scatter + fp32 row GEMM) if ws/shape checks fail
// ---------------------------------------------------------------------------
__global__ void scatter_kernel(const int* __restrict__ src, const int* __restrict__ dst,
                               const float* __restrict__ w, const float* __restrict__ data,
                               float* __restrict__ agg, int E) {
    int tid = blockIdx.x * blockDim.x + threadIdx.x;
    int e = tid >> 6;
    int d = tid & 63;
    if (e >= E) return;
    float val = w[e] * data[(size_t)src[e] * D + d];
    atomicAdd(&agg[(size_t)dst[e] * D + d], val);
}

__global__ __launch_bounds__(256, 4) void rowgemm_f32_kernel(const float* __restrict__ A,
                                                             const float* __restrict__ theta,
                                                             float* __restrict__ out, int N) {
    __shared__ float th[D * D];
    __shared__ float at[D][68];
    int t = threadIdx.x;
    int rowBase = blockIdx.x * 64;
#pragma unroll
    for (int i = 0; i < 4; ++i) {
        int f = t + i * 256;
        ((float4*)th)[f] = ((const float4*)theta)[f];
    }
#pragma unroll
    for (int i = 0; i < 4; ++i) {
        int f = t + i * 256;
        int row = f >> 4;
        int kv = f & 15;
        float4 v = make_float4(0.f, 0.f, 0.f, 0.f);
        if (rowBase + row < N) v = *(const float4*)&A[(size_t)(rowBase + row) * D + kv * 4];
        at[kv * 4 + 0][row] = v.x;
        at[kv * 4 + 1][row] = v.y;
        at[kv * 4 + 2][row] = v.z;
        at[kv * 4 + 3][row] = v.w;
    }
    __syncthreads();
    int c0 = (t & 15) * 4;
    int r0 = (t >> 4) * 4;
    float4 acc0 = make_float4(0.f, 0.f, 0.f, 0.f);
    float4 acc1 = acc0, acc2 = acc0, acc3 = acc0;
#pragma unroll 16
    for (int kk = 0; kk < D; ++kk) {
        float4 bv = *(const float4*)&th[kk * D + c0];
        float4 av = *(const float4*)&at[kk][r0];
        acc0.x += av.x * bv.x; acc0.y += av.x * bv.y; acc0.z += av.x * bv.z; acc0.w += av.x * bv.w;
        acc1.x += av.y * bv.x; acc1.y += av.y * bv.y; acc1.z += av.y * bv.z; acc1.w += av.y * bv.w;
        acc2.x += av.z * bv.x; acc2.y += av.z * bv.y; acc2.z += av.z * bv.z; acc2.w += av.z * bv.w;
        acc3.x += av.w * bv.x; acc3.y += av.w * bv.y; acc3.z += av.w * bv.z; acc3.w += av.w * bv.w;
    }
    float4 accs[4] = {acc0, acc1, acc2, acc3};
#pragma unroll
    for (int i = 0; i < 4; ++i) {
        int r = rowBase + r0 + i;
        if (r < N) *(float4*)&out[(size_t)r * D + c0] = accs[i];
    }
}

extern "C" void kernel_launch(void* const* d_in, const int* in_sizes, int n_in,
                              void* d_out, int out_size, void* d_ws, size_t ws_size,
                              hipStream_t stream) {
    const int*   src   = (const int*)d_in[0];
    const int*   dst   = (const int*)d_in[1];
    const float* w     = (const float*)d_in[2];
    const float* data  = (const float*)d_in[3];
    const float* theta = (const float*)d_in[4];
    const int E = in_sizes[0];
    const int N = in_sizes[3] / D;
    float* out = (float*)d_out;

    const int B = (N + NPB - 1) / NPB;

    // ws layout: proj16 (bf16, adjacent-pair words) | adjB (B*CAPB int2) |
    //            ovf (E int4) | cursor[B] | ovfCnt
    size_t projBytes = (size_t)N * D * 2;
    size_t adjBytes  = (size_t)B * CAPB * 8;
    size_t ovfBytes  = (size_t)E * 16;
    size_t need = projBytes + adjBytes + ovfBytes + ((size_t)B + 1) * 4 + 256;

    if (ws_size >= need && N < (1 << 20) && B <= MAXB) {
        unsigned short* proj16 = (unsigned short*)d_ws;
        int2* adjB   = (int2*)((char*)d_ws + projBytes);
        int4* ovf    = (int4*)((char*)d_ws + projBytes + adjBytes);
        int*  cursor = (int*)((char*)d_ws + projBytes + adjBytes + ovfBytes);
        int*  ovfCnt = cursor + B;

        int gs = (E + CHUNK_MAX - 1) / CHUNK_MAX;  // chunk <= CHUNK_MAX

        zero_i_kernel<<<(B + 1 + 255) / 256, 256, 0, stream>>>(cursor, B + 1);
        bucket_scatter_kernel<<<gs, SCATTER_T, 0, stream>>>(src, dst, w, cursor,
                                                            ovfCnt, ovf, adjB, E, B);
        rowgemm_bf16_kernel<<<(N + 63) / 64, 256, 0, stream>>>(data, theta, proj16, N);
        sort_gather_kernel<<<B, GT, 0, stream>>>(adjB, cursor, ovfCnt, ovf,
                                                 (const unsigned*)proj16, out, N);
    } else {
        float* agg = (float*)d_ws;
        int n4 = (N * D) / 4;
        zero_f4_kernel<<<(n4 + 255) / 256, 256, 0, stream>>>((float4*)agg, n4);
        long long total = (long long)E * D;
        scatter_kernel<<<(int)((total + 255) / 256), 256, 0, stream>>>(src, dst, w, data, agg, E);
        rowgemm_f32_kernel<<<(N + 63) / 64, 256, 0, stream>>>(agg, theta, out, N);
    }
}